// Round 3
// baseline (1927.070 us; speedup 1.0000x reference)
//
#include <hip/hip_runtime.h>
#include <hip/hip_bf16.h>

#define DD 128
#define NHEAD 4
#define CHAN 32
#define NEG 0.2f

// ---------------- atom encoder: h[n,d] = sum_f tab[f, x[n,f], d] ----------------
__global__ void k_atom_enc(const int* __restrict__ x, const float* __restrict__ tab,
                           float* __restrict__ h, int N) {
  int idx = blockIdx.x * blockDim.x + threadIdx.x;
  if (idx >= N * DD) return;
  int n = idx >> 7, d = idx & 127;
  const int* xr = x + n * 9;
  float s = 0.f;
#pragma unroll
  for (int f = 0; f < 9; f++) {
    int v = xr[f];
    s += tab[(f * 16 + v) * DD + d];
  }
  h[idx] = s;
}

// ---------------- init deg(=1 self loop), cnt, sums ----------------
__global__ void k_init(int* __restrict__ deg, float* __restrict__ cnt,
                       float* __restrict__ sums, int N) {
  int i = blockIdx.x * blockDim.x + threadIdx.x;
  if (i >= N) return;
  deg[i] = 1;
  cnt[i] = 0.f;
  sums[i * 4 + 0] = 0.f; sums[i * 4 + 1] = 0.f;
  sums[i * 4 + 2] = 0.f; sums[i * 4 + 3] = 0.f;
}

// ---------------- per real edge: bond emb, per-dst sums/cnt/deg ----------------
__global__ void k_edge_count(const int* __restrict__ ei, const int* __restrict__ eattr,
                             const float* __restrict__ btab, float* __restrict__ e_emb,
                             float* __restrict__ sums, float* __restrict__ cnt,
                             int* __restrict__ deg, int E) {
  int e = blockIdx.x * blockDim.x + threadIdx.x;
  if (e >= E) return;
  int d = ei[E + e];
  int a = eattr[e];
  float f0 = btab[a * 4 + 0], f1 = btab[a * 4 + 1];
  float f2 = btab[a * 4 + 2], f3 = btab[a * 4 + 3];
  e_emb[e * 4 + 0] = f0; e_emb[e * 4 + 1] = f1;
  e_emb[e * 4 + 2] = f2; e_emb[e * 4 + 3] = f3;
  atomicAdd(&sums[d * 4 + 0], f0);
  atomicAdd(&sums[d * 4 + 1], f1);
  atomicAdd(&sums[d * 4 + 2], f2);
  atomicAdd(&sums[d * 4 + 3], f3);
  atomicAdd(&cnt[d], 1.0f);
  atomicAdd(&deg[d], 1);
}

// ---------------- loop_attr (in-place on sums) ----------------
__global__ void k_loopattr(float* __restrict__ sums, const float* __restrict__ cnt, int N) {
  int i = blockIdx.x * blockDim.x + threadIdx.x;
  if (i >= N * 4) return;
  sums[i] = sums[i] / fmaxf(cnt[i >> 2], 1.0f);
}

// ---------------- scan: chunk = 2048 (256 thr x 8 items) ----------------
__global__ void k_scan_block(const int* __restrict__ deg, int* __restrict__ bsums, int N) {
  __shared__ int sh[256];
  int t = threadIdx.x;
  int base = blockIdx.x * 2048 + t * 8;
  int tot = 0;
#pragma unroll
  for (int i = 0; i < 8; i++) tot += (base + i < N) ? deg[base + i] : 0;
  sh[t] = tot;
  __syncthreads();
  for (int off = 128; off > 0; off >>= 1) {
    if (t < off) sh[t] += sh[t + off];
    __syncthreads();
  }
  if (t == 0) bsums[blockIdx.x] = sh[0];
}

__global__ void k_scan_top(int* __restrict__ bsums, int* __restrict__ rowptr,
                           int nblk, int N) {
  if (threadIdx.x == 0 && blockIdx.x == 0) {
    int run = 0;
    for (int b = 0; b < nblk; b++) { int v = bsums[b]; bsums[b] = run; run += v; }
    rowptr[N] = run;
  }
}

__global__ void k_scan_down(const int* __restrict__ deg, const int* __restrict__ bsums,
                            int* __restrict__ rowptr, int* __restrict__ cursor, int N) {
  __shared__ int sh[256];
  int t = threadIdx.x;
  int base = blockIdx.x * 2048 + t * 8;
  int v[8]; int tot = 0;
#pragma unroll
  for (int i = 0; i < 8; i++) { v[i] = (base + i < N) ? deg[base + i] : 0; tot += v[i]; }
  sh[t] = tot;
  __syncthreads();
  // Hillis-Steele inclusive scan
  for (int off = 1; off < 256; off <<= 1) {
    int xv = (t >= off) ? sh[t - off] : 0;
    __syncthreads();
    sh[t] += xv;
    __syncthreads();
  }
  int run = bsums[blockIdx.x] + sh[t] - tot;
#pragma unroll
  for (int i = 0; i < 8; i++) {
    if (base + i < N) { rowptr[base + i] = run; cursor[base + i] = run; run += v[i]; }
  }
}

// ---------------- scatter edge ids into CSR (order within segment irrelevant) -----
__global__ void k_scatter(const int* __restrict__ ei, int* __restrict__ cursor,
                          int* __restrict__ eid, int E, int N) {
  int t = blockIdx.x * blockDim.x + threadIdx.x;
  if (t >= E + N) return;
  int d = (t < E) ? ei[E + t] : (t - E);
  int pos = atomicAdd(&cursor[d], 1);
  eid[pos] = t;
}

// ---------------- fused xl/xr GEMM: [64 atoms] x [128 out] x 2 mats --------------
// NOTE: xr may ALIAS h. Safe: all h reads for this block's rows complete before
// __syncthreads(); all stores data-depend on those reads (via LDS); blocks own
// disjoint row ranges. No __restrict__ on h/xl/xr.
__global__ __launch_bounds__(256) void k_gemm2(const float* h,
    const float* __restrict__ Wl, const float* __restrict__ bl,
    const float* __restrict__ Wr, const float* __restrict__ br,
    float* xl, float* xr, int N) {
  __shared__ float hT[128][68];
  int t = threadIdx.x;
  int A0 = blockIdx.x * 64;
  {
    int a = t >> 2;             // 0..63
    int kq = (t & 3) * 32;      // 32 k's per thread
    int n = A0 + a;
#pragma unroll
    for (int i = 0; i < 8; i++) {
      float4 v = make_float4(0.f, 0.f, 0.f, 0.f);
      if (n < N) v = *(const float4*)&h[(size_t)n * DD + kq + i * 4];
      int k = kq + i * 4;
      hT[k + 0][a] = v.x; hT[k + 1][a] = v.y;
      hT[k + 2][a] = v.z; hT[k + 3][a] = v.w;
    }
  }
  __syncthreads();
  int tx = t & 15, ty = t >> 4;
  int d0 = tx * 8, a0 = ty * 4;
  float accl[4][8], accr[4][8];
#pragma unroll
  for (int j = 0; j < 8; j++) {
    float bLv = bl[d0 + j], bRv = br[d0 + j];
#pragma unroll
    for (int i = 0; i < 4; i++) { accl[i][j] = bLv; accr[i][j] = bRv; }
  }
#pragma unroll 2
  for (int kk = 0; kk < 128; kk++) {
    float4 ha4 = *(const float4*)&hT[kk][a0];
    float hv[4] = {ha4.x, ha4.y, ha4.z, ha4.w};
    const float* wlp = &Wl[kk * DD + d0];
    const float* wrp = &Wr[kk * DD + d0];
    float4 wl0 = *(const float4*)(wlp);
    float4 wl1 = *(const float4*)(wlp + 4);
    float4 wr0 = *(const float4*)(wrp);
    float4 wr1 = *(const float4*)(wrp + 4);
    float wlv[8] = {wl0.x, wl0.y, wl0.z, wl0.w, wl1.x, wl1.y, wl1.z, wl1.w};
    float wrv[8] = {wr0.x, wr0.y, wr0.z, wr0.w, wr1.x, wr1.y, wr1.z, wr1.w};
#pragma unroll
    for (int i = 0; i < 4; i++) {
#pragma unroll
      for (int j = 0; j < 8; j++) {
        accl[i][j] += hv[i] * wlv[j];
        accr[i][j] += hv[i] * wrv[j];
      }
    }
  }
#pragma unroll
  for (int i = 0; i < 4; i++) {
    int n = A0 + a0 + i;
    if (n < N) {
      *(float4*)&xl[(size_t)n * DD + d0]     = make_float4(accl[i][0], accl[i][1], accl[i][2], accl[i][3]);
      *(float4*)&xl[(size_t)n * DD + d0 + 4] = make_float4(accl[i][4], accl[i][5], accl[i][6], accl[i][7]);
      *(float4*)&xr[(size_t)n * DD + d0]     = make_float4(accr[i][0], accr[i][1], accr[i][2], accr[i][3]);
      *(float4*)&xr[(size_t)n * DD + d0 + 4] = make_float4(accr[i][4], accr[i][5], accr[i][6], accr[i][7]);
    }
  }
}

// ---------------- node-parallel attention with online softmax --------------------
// one wave per node, 2 channels per lane, 16-lane butterfly per head
// NOTE: xr and hout may ALIAS (wave reads only its own row at start, writes its
// own row at end; no cross-row reads of that buffer). No __restrict__ on them.
__global__ __launch_bounds__(256) void k_attn(
    const float* __restrict__ xl, const float* xr,
    const float* __restrict__ e_emb, const float* __restrict__ la,
    const int* __restrict__ ei, const int* __restrict__ rowptr,
    const int* __restrict__ eid,
    const float* __restrict__ Wep, const float* __restrict__ attp,
    const float* __restrict__ cbp,
    float* hout, int N, int E, int relu_flag) {
  int wid = threadIdx.x >> 6;
  int lane = threadIdx.x & 63;
  int n = blockIdx.x * 4 + wid;
  if (n >= N) return;
  int d0 = lane * 2;
  float we0[4], we1[4];
#pragma unroll
  for (int j = 0; j < 4; j++) {
    we0[j] = Wep[j * DD + d0];
    we1[j] = Wep[j * DD + d0 + 1];
  }
  int hh = lane >> 4;
  float a0 = attp[hh * 32 + (d0 & 31)];
  float a1 = attp[hh * 32 + ((d0 + 1) & 31)];
  float2 xr2 = *(const float2*)&xr[(size_t)n * DD + d0];
  float m = -3.0e38f, z = 0.f, acc0 = 0.f, acc1 = 0.f;
  int r0 = rowptr[n], r1 = rowptr[n + 1];
  for (int p = r0; p < r1; p++) {
    int e = eid[p];
    int s; float f0, f1, f2, f3;
    if (e < E) {
      s = ei[e];
      const float* fp = &e_emb[(size_t)e * 4];
      f0 = fp[0]; f1 = fp[1]; f2 = fp[2]; f3 = fp[3];
    } else {
      s = n;
      const float* fp = &la[(size_t)n * 4];
      f0 = fp[0]; f1 = fp[1]; f2 = fp[2]; f3 = fp[3];
    }
    float2 xv = *(const float2*)&xl[(size_t)s * DD + d0];
    float ee0 = f0 * we0[0] + f1 * we0[1] + f2 * we0[2] + f3 * we0[3];
    float ee1 = f0 * we1[0] + f1 * we1[1] + f2 * we1[2] + f3 * we1[3];
    float g0 = xv.x + xr2.x + ee0; g0 = g0 > 0.f ? g0 : NEG * g0;
    float g1 = xv.y + xr2.y + ee1; g1 = g1 > 0.f ? g1 : NEG * g1;
    float pv = g0 * a0 + g1 * a1;
    pv += __shfl_xor(pv, 1);
    pv += __shfl_xor(pv, 2);
    pv += __shfl_xor(pv, 4);
    pv += __shfl_xor(pv, 8);
    float mn = fmaxf(m, pv);
    float sc = __expf(m - mn);
    float w  = __expf(pv - mn);
    z = z * sc + w;
    acc0 = acc0 * sc + w * xv.x;
    acc1 = acc1 * sc + w * xv.y;
    m = mn;
  }
  float inv = 1.f / (z + 1e-16f);
  float o0 = acc0 * inv + cbp[d0];
  float o1 = acc1 * inv + cbp[d0 + 1];
  if (relu_flag) { o0 = fmaxf(o0, 0.f); o1 = fmaxf(o1, 0.f); }
  *(float2*)&hout[(size_t)n * DD + d0] = make_float2(o0, o1);
}

// ---------------- head: out[g] = bout + sum_{n in g} h[n].Wout -------------------
__global__ void k_head_init(float* __restrict__ out, const float* __restrict__ bout, int G) {
  int i = blockIdx.x * blockDim.x + threadIdx.x;
  if (i < G) out[i] = bout[0];
}

__global__ __launch_bounds__(256) void k_head(const float* __restrict__ h,
    const int* __restrict__ bid, const float* __restrict__ Wout,
    float* __restrict__ out, int N) {
  int n = blockIdx.x * 4 + (threadIdx.x >> 6);
  if (n >= N) return;
  int lane = threadIdx.x & 63, d0 = lane * 2;
  float2 hv = *(const float2*)&h[(size_t)n * DD + d0];
  float v = hv.x * Wout[d0] + hv.y * Wout[d0 + 1];
  v += __shfl_xor(v, 1);
  v += __shfl_xor(v, 2);
  v += __shfl_xor(v, 4);
  v += __shfl_xor(v, 8);
  v += __shfl_xor(v, 16);
  v += __shfl_xor(v, 32);
  if (lane == 0) atomicAdd(&out[bid[n]], v);
}

extern "C" void kernel_launch(void* const* d_in, const int* in_sizes, int n_in,
                              void* d_out, int out_size, void* d_ws, size_t ws_size,
                              hipStream_t stream) {
  const float* atom_tables = (const float*)d_in[0];
  const float* bond_table  = (const float*)d_in[1];
  const float* Wl   = (const float*)d_in[2];
  const float* bl   = (const float*)d_in[3];
  const float* Wr   = (const float*)d_in[4];
  const float* br   = (const float*)d_in[5];
  const float* We   = (const float*)d_in[6];
  const float* att  = (const float*)d_in[7];
  const float* cb   = (const float*)d_in[8];
  const float* Wout = (const float*)d_in[9];
  const float* bout = (const float*)d_in[10];
  const int* x      = (const int*)d_in[11];
  const int* ei     = (const int*)d_in[12];
  const int* eattr  = (const int*)d_in[13];
  const int* bid    = (const int*)d_in[14];

  int N = in_sizes[11] / 9;
  int E = in_sizes[13];
  int G = out_size;          // NTASK == 1
  int L = in_sizes[3] / DD;  // 4 layers

  char* p = (char*)d_ws;
  auto alloc = [&](size_t bytes) {
    char* r = p;
    p += (bytes + 255) & ~(size_t)255;
    return r;
  };
  // hx: h input / xr / h output (aliased — see kernel notes). 102.4 MB
  float* hx     = (float*)alloc((size_t)N * DD * 4);
  float* xl     = (float*)alloc((size_t)N * DD * 4);   // 102.4 MB
  float* e_emb  = (float*)alloc((size_t)E * 4 * 4);    // 6.4 MB
  float* sums   = (float*)alloc((size_t)N * 4 * 4);    // loop_attr, 3.2 MB
  int*   rowptr = (int*)alloc((size_t)(N + 1) * 4);
  int*   eid    = (int*)alloc((size_t)(E + N) * 4);
  float* cnt    = (float*)alloc((size_t)N * 4);
  int*   deg    = (int*)alloc((size_t)N * 4);
  int*   cursor = (int*)alloc((size_t)N * 4);
  int nblk = (N + 2047) / 2048;
  int*   bsums  = (int*)alloc((size_t)nblk * 4);
  float* out    = (float*)d_out;

  // Diagnostic guard: if workspace is too small, launch nothing -> clean
  // absmax failure instead of a GPU memory fault.
  if ((size_t)(p - (char*)d_ws) > ws_size) return;

  hipLaunchKernelGGL(k_atom_enc, dim3((N * DD + 255) / 256), dim3(256), 0, stream,
                     x, atom_tables, hx, N);
  hipLaunchKernelGGL(k_init, dim3((N + 255) / 256), dim3(256), 0, stream,
                     deg, cnt, sums, N);
  hipLaunchKernelGGL(k_edge_count, dim3((E + 255) / 256), dim3(256), 0, stream,
                     ei, eattr, bond_table, e_emb, sums, cnt, deg, E);
  hipLaunchKernelGGL(k_scan_block, dim3(nblk), dim3(256), 0, stream, deg, bsums, N);
  hipLaunchKernelGGL(k_scan_top, dim3(1), dim3(64), 0, stream, bsums, rowptr, nblk, N);
  hipLaunchKernelGGL(k_scan_down, dim3(nblk), dim3(256), 0, stream,
                     deg, bsums, rowptr, cursor, N);
  hipLaunchKernelGGL(k_scatter, dim3((E + N + 255) / 256), dim3(256), 0, stream,
                     ei, cursor, eid, E, N);
  hipLaunchKernelGGL(k_loopattr, dim3((N * 4 + 255) / 256), dim3(256), 0, stream,
                     sums, cnt, N);

  for (int l = 0; l < L; l++) {
    // writes xl, and xr -> hx (aliases input h; safe, see kernel note)
    hipLaunchKernelGGL(k_gemm2, dim3((N + 63) / 64), dim3(256), 0, stream,
                       hx, Wl + (size_t)l * DD * DD, bl + (size_t)l * DD,
                       Wr + (size_t)l * DD * DD, br + (size_t)l * DD, xl, hx, N);
    // reads xr from hx (own row), writes new h into hx (own row)
    hipLaunchKernelGGL(k_attn, dim3((N + 3) / 4), dim3(256), 0, stream,
                       xl, hx, e_emb, sums, ei, rowptr, eid,
                       We + (size_t)l * NHEAD * DD, att + (size_t)l * NHEAD * CHAN,
                       cb + (size_t)l * DD, hx, N, E, (l < L - 1) ? 1 : 0);
  }

  hipLaunchKernelGGL(k_head_init, dim3((G + 255) / 256), dim3(256), 0, stream,
                     out, bout, G);
  hipLaunchKernelGGL(k_head, dim3((N + 3) / 4), dim3(256), 0, stream,
                     hx, bid, Wout, out, N);
}

// Round 5
// 1296.120 us; speedup vs baseline: 1.4868x; 1.4868x over previous
//
#include <hip/hip_runtime.h>
#include <hip/hip_bf16.h>

#define DD 128
#define NHEAD 4
#define CHAN 32
#define NEG 0.2f

typedef short bf16x8 __attribute__((ext_vector_type(8)));
typedef float f32x4 __attribute__((ext_vector_type(4)));

__device__ inline ushort f2bf(float x) {
  unsigned u = __float_as_uint(x);
  return (ushort)((u + 0x7FFF + ((u >> 16) & 1)) >> 16);
}

// ---------------- atom encoder: h[n,d] = sum_f tab[f, x[n,f], d] ----------------
__global__ void k_atom_enc(const int* __restrict__ x, const float* __restrict__ tab,
                           float* __restrict__ h, int N) {
  int idx = blockIdx.x * blockDim.x + threadIdx.x;
  if (idx >= N * DD) return;
  int n = idx >> 7, d = idx & 127;
  const int* xr = x + n * 9;
  float s = 0.f;
#pragma unroll
  for (int f = 0; f < 9; f++) {
    int v = xr[f];
    s += tab[(f * 16 + v) * DD + d];
  }
  h[idx] = s;
}

// ---------------- init deg(=1 self loop), cnt, sums ----------------
__global__ void k_init(int* __restrict__ deg, float* __restrict__ cnt,
                       float* __restrict__ sums, int N) {
  int i = blockIdx.x * blockDim.x + threadIdx.x;
  if (i >= N) return;
  deg[i] = 1;
  cnt[i] = 0.f;
  sums[i * 4 + 0] = 0.f; sums[i * 4 + 1] = 0.f;
  sums[i * 4 + 2] = 0.f; sums[i * 4 + 3] = 0.f;
}

// ---------------- per real edge: bond emb, per-dst sums/cnt/deg ----------------
__global__ void k_edge_count(const int* __restrict__ ei, const int* __restrict__ eattr,
                             const float* __restrict__ btab, float* __restrict__ e_emb,
                             float* __restrict__ sums, float* __restrict__ cnt,
                             int* __restrict__ deg, int E) {
  int e = blockIdx.x * blockDim.x + threadIdx.x;
  if (e >= E) return;
  int d = ei[E + e];
  int a = eattr[e];
  float f0 = btab[a * 4 + 0], f1 = btab[a * 4 + 1];
  float f2 = btab[a * 4 + 2], f3 = btab[a * 4 + 3];
  e_emb[e * 4 + 0] = f0; e_emb[e * 4 + 1] = f1;
  e_emb[e * 4 + 2] = f2; e_emb[e * 4 + 3] = f3;
  atomicAdd(&sums[d * 4 + 0], f0);
  atomicAdd(&sums[d * 4 + 1], f1);
  atomicAdd(&sums[d * 4 + 2], f2);
  atomicAdd(&sums[d * 4 + 3], f3);
  atomicAdd(&cnt[d], 1.0f);
  atomicAdd(&deg[d], 1);
}

// ---------------- loop_attr (in-place on sums) ----------------
__global__ void k_loopattr(float* __restrict__ sums, const float* __restrict__ cnt, int N) {
  int i = blockIdx.x * blockDim.x + threadIdx.x;
  if (i >= N * 4) return;
  sums[i] = sums[i] / fmaxf(cnt[i >> 2], 1.0f);
}

// ---------------- scan: chunk = 2048 (256 thr x 8 items) ----------------
__global__ void k_scan_block(const int* __restrict__ deg, int* __restrict__ bsums, int N) {
  __shared__ int sh[256];
  int t = threadIdx.x;
  int base = blockIdx.x * 2048 + t * 8;
  int tot = 0;
#pragma unroll
  for (int i = 0; i < 8; i++) tot += (base + i < N) ? deg[base + i] : 0;
  sh[t] = tot;
  __syncthreads();
  for (int off = 128; off > 0; off >>= 1) {
    if (t < off) sh[t] += sh[t + off];
    __syncthreads();
  }
  if (t == 0) bsums[blockIdx.x] = sh[0];
}

__global__ void k_scan_top(int* __restrict__ bsums, int* __restrict__ rowptr,
                           int nblk, int N) {
  if (threadIdx.x == 0 && blockIdx.x == 0) {
    int run = 0;
    for (int b = 0; b < nblk; b++) { int v = bsums[b]; bsums[b] = run; run += v; }
    rowptr[N] = run;
  }
}

__global__ void k_scan_down(const int* __restrict__ deg, const int* __restrict__ bsums,
                            int* __restrict__ rowptr, int* __restrict__ cursor, int N) {
  __shared__ int sh[256];
  int t = threadIdx.x;
  int base = blockIdx.x * 2048 + t * 8;
  int v[8]; int tot = 0;
#pragma unroll
  for (int i = 0; i < 8; i++) { v[i] = (base + i < N) ? deg[base + i] : 0; tot += v[i]; }
  sh[t] = tot;
  __syncthreads();
  // Hillis-Steele inclusive scan
  for (int off = 1; off < 256; off <<= 1) {
    int xv = (t >= off) ? sh[t - off] : 0;
    __syncthreads();
    sh[t] += xv;
    __syncthreads();
  }
  int run = bsums[blockIdx.x] + sh[t] - tot;
#pragma unroll
  for (int i = 0; i < 8; i++) {
    if (base + i < N) { rowptr[base + i] = run; cursor[base + i] = run; run += v[i]; }
  }
}

// ---------------- scatter edge ids into CSR (order within segment irrelevant) -----
__global__ void k_scatter(const int* __restrict__ ei, int* __restrict__ cursor,
                          int* __restrict__ eid, int E, int N) {
  int t = blockIdx.x * blockDim.x + threadIdx.x;
  if (t >= E + N) return;
  int d = (t < E) ? ei[E + t] : (t - E);
  int pos = atomicAdd(&cursor[d], 1);
  eid[pos] = t;
}

// ---------------- W prepack: bf16 hi/lo split into MFMA fragment order -----------
// B frag for (layer,mat,kb,nt): lane l, elem j holds W[kb*32+(l>>4)*8+j][nt*16+(l&15)]
// stored contiguously so the GEMM reads one 16B load per frag.
__global__ void k_wpack(const float* __restrict__ Wl, const float* __restrict__ Wr,
                        ushort* __restrict__ Bhi, ushort* __restrict__ Blo, int L) {
  int tid = blockIdx.x * blockDim.x + threadIdx.x;
  int total = L * 2 * 4 * 8 * 64;
  if (tid >= total) return;
  int lane = tid & 63;
  int nt = (tid >> 6) & 7;
  int kb = (tid >> 9) & 3;
  int mat = (tid >> 11) & 1;
  int layer = tid >> 12;
  const float* W = (mat ? Wr : Wl) + (size_t)layer * DD * DD;
  int kbase = kb * 32 + (lane >> 4) * 8;
  int n = nt * 16 + (lane & 15);
  size_t out = (size_t)(layer * 2 + mat) * 16384 +
               ((size_t)(kb * 8 + nt) * 64 + lane) * 8;
#pragma unroll
  for (int j = 0; j < 8; j++) {
    float xv = W[(size_t)(kbase + j) * DD + n];
    ushort h_ = f2bf(xv);
    float fh = __uint_as_float((unsigned)h_ << 16);
    ushort l_ = f2bf(xv - fh);
    Bhi[out + j] = h_;
    Blo[out + j] = l_;
  }
}

// ---------------- fused xl/xr GEMM via bf16x3 MFMA ------------------------------
// 64 atoms x 128 outs x K=128, both mats. 4 waves; wave w: 4 M-tiles x N-tiles
// {2w,2w+1} x 2 mats. A staged in LDS as hi/lo bf16, XOR-swizzled (conflict-free
// ds_read_b128). B frags streamed from prepacked global (L2-hot, 16B/lane).
// NOTE: xr may ALIAS h (all h reads precede __syncthreads; stores data-depend).
__global__ __launch_bounds__(256) void k_gemm2_mfma(const float* h,
    const ushort* __restrict__ bhiL, const ushort* __restrict__ bloL,
    const ushort* __restrict__ bhiR, const ushort* __restrict__ bloR,
    const float* __restrict__ bl, const float* __restrict__ br,
    float* xl, float* xr, int N) {
  __shared__ ushort sAhi[64 * 128];
  __shared__ ushort sAlo[64 * 128];
  int t = threadIdx.x;
  int A0 = blockIdx.x * 64;
  // ---- stage h tile, split to bf16 hi/lo in LDS ----
  {
    int a = t >> 2;
    int kq = (t & 3) * 32;
    int n = A0 + a;
    const float* hp = &h[(size_t)n * DD + kq];
    int swz = (a & 7) << 4;
    int rowb = a * 256;
#pragma unroll
    for (int i = 0; i < 8; i++) {
      float4 v = (n < N) ? *(const float4*)(hp + i * 4) : make_float4(0, 0, 0, 0);
      float fv[4] = {v.x, v.y, v.z, v.w};
      ushort hiw[4], low[4];
#pragma unroll
      for (int j = 0; j < 4; j++) {
        ushort h_ = f2bf(fv[j]);
        float fh = __uint_as_float((unsigned)h_ << 16);
        hiw[j] = h_;
        low[j] = f2bf(fv[j] - fh);
      }
      int inrow = (kq + i * 4) * 2;           // byte offset within 256B row
      int off = rowb + (inrow ^ swz);
      *(ushort4*)((char*)sAhi + off) = make_ushort4(hiw[0], hiw[1], hiw[2], hiw[3]);
      *(ushort4*)((char*)sAlo + off) = make_ushort4(low[0], low[1], low[2], low[3]);
    }
  }
  __syncthreads();

  int lane = t & 63;
  int w = t >> 6;
  int arow = lane & 15;
  int acol = (lane >> 4) * 16;                // byte offset of k-group within row
  int swzr = (arow & 7) << 4;

  f32x4 accL[4][2], accR[4][2];
#pragma unroll
  for (int mt = 0; mt < 4; mt++)
#pragma unroll
    for (int nti = 0; nti < 2; nti++) {
      accL[mt][nti] = (f32x4){0.f, 0.f, 0.f, 0.f};
      accR[mt][nti] = (f32x4){0.f, 0.f, 0.f, 0.f};
    }

  for (int kb = 0; kb < 4; kb++) {
    bf16x8 ahi[4], alo[4];
#pragma unroll
    for (int mt = 0; mt < 4; mt++) {
      int abyte = (mt * 16 + arow) * 256 + ((kb * 64 + acol) ^ swzr);
      ahi[mt] = *(const bf16x8*)((const char*)sAhi + abyte);
      alo[mt] = *(const bf16x8*)((const char*)sAlo + abyte);
    }
#pragma unroll
    for (int nti = 0; nti < 2; nti++) {
      int nt = w * 2 + nti;
      size_t fo = ((size_t)(kb * 8 + nt) * 64 + lane) * 8;
      bf16x8 bhl = *(const bf16x8*)(bhiL + fo);
      bf16x8 bll = *(const bf16x8*)(bloL + fo);
      bf16x8 bhr = *(const bf16x8*)(bhiR + fo);
      bf16x8 blr = *(const bf16x8*)(bloR + fo);
#pragma unroll
      for (int mt = 0; mt < 4; mt++) {
        accL[mt][nti] = __builtin_amdgcn_mfma_f32_16x16x32_bf16(ahi[mt], bhl, accL[mt][nti], 0, 0, 0);
        accR[mt][nti] = __builtin_amdgcn_mfma_f32_16x16x32_bf16(ahi[mt], bhr, accR[mt][nti], 0, 0, 0);
        accL[mt][nti] = __builtin_amdgcn_mfma_f32_16x16x32_bf16(ahi[mt], bll, accL[mt][nti], 0, 0, 0);
        accR[mt][nti] = __builtin_amdgcn_mfma_f32_16x16x32_bf16(ahi[mt], blr, accR[mt][nti], 0, 0, 0);
        accL[mt][nti] = __builtin_amdgcn_mfma_f32_16x16x32_bf16(alo[mt], bhl, accL[mt][nti], 0, 0, 0);
        accR[mt][nti] = __builtin_amdgcn_mfma_f32_16x16x32_bf16(alo[mt], bhr, accR[mt][nti], 0, 0, 0);
      }
    }
  }

  // ---- epilogue: D row=(lane>>4)*4+r, col=lane&15 ----
  int col = lane & 15;
  int rgrp = (lane >> 4) * 4;
#pragma unroll
  for (int nti = 0; nti < 2; nti++) {
    int n = (w * 2 + nti) * 16 + col;
    float bLv = bl[n], bRv = br[n];
#pragma unroll
    for (int mt = 0; mt < 4; mt++) {
#pragma unroll
      for (int r = 0; r < 4; r++) {
        int atom = A0 + mt * 16 + rgrp + r;
        if (atom < N) {
          xl[(size_t)atom * DD + n] = accL[mt][nti][r] + bLv;
          xr[(size_t)atom * DD + n] = accR[mt][nti][r] + bRv;
        }
      }
    }
  }
}

// ---------------- node-parallel attention with online softmax --------------------
// NOTE: xr and hout may ALIAS (wave reads only its own row at start, writes its
// own row at end; no cross-row reads of that buffer). No __restrict__ on them.
__global__ __launch_bounds__(256) void k_attn(
    const float* __restrict__ xl, const float* xr,
    const float* __restrict__ e_emb, const float* __restrict__ la,
    const int* __restrict__ ei, const int* __restrict__ rowptr,
    const int* __restrict__ eid,
    const float* __restrict__ Wep, const float* __restrict__ attp,
    const float* __restrict__ cbp,
    float* hout, int N, int E, int relu_flag) {
  int wid = threadIdx.x >> 6;
  int lane = threadIdx.x & 63;
  int n = blockIdx.x * 4 + wid;
  if (n >= N) return;
  int d0 = lane * 2;
  float we0[4], we1[4];
#pragma unroll
  for (int j = 0; j < 4; j++) {
    we0[j] = Wep[j * DD + d0];
    we1[j] = Wep[j * DD + d0 + 1];
  }
  int hh = lane >> 4;
  float a0 = attp[hh * 32 + (d0 & 31)];
  float a1 = attp[hh * 32 + ((d0 + 1) & 31)];
  float2 xr2 = *(const float2*)&xr[(size_t)n * DD + d0];
  float m = -3.0e38f, z = 0.f, acc0 = 0.f, acc1 = 0.f;
  int r0 = rowptr[n], r1 = rowptr[n + 1];
  for (int p = r0; p < r1; p++) {
    int e = eid[p];
    int s; float f0, f1, f2, f3;
    if (e < E) {
      s = ei[e];
      const float* fp = &e_emb[(size_t)e * 4];
      f0 = fp[0]; f1 = fp[1]; f2 = fp[2]; f3 = fp[3];
    } else {
      s = n;
      const float* fp = &la[(size_t)n * 4];
      f0 = fp[0]; f1 = fp[1]; f2 = fp[2]; f3 = fp[3];
    }
    float2 xv = *(const float2*)&xl[(size_t)s * DD + d0];
    float ee0 = f0 * we0[0] + f1 * we0[1] + f2 * we0[2] + f3 * we0[3];
    float ee1 = f0 * we1[0] + f1 * we1[1] + f2 * we1[2] + f3 * we1[3];
    float g0 = xv.x + xr2.x + ee0; g0 = g0 > 0.f ? g0 : NEG * g0;
    float g1 = xv.y + xr2.y + ee1; g1 = g1 > 0.f ? g1 : NEG * g1;
    float pv = g0 * a0 + g1 * a1;
    pv += __shfl_xor(pv, 1);
    pv += __shfl_xor(pv, 2);
    pv += __shfl_xor(pv, 4);
    pv += __shfl_xor(pv, 8);
    float mn = fmaxf(m, pv);
    float sc = __expf(m - mn);
    float w  = __expf(pv - mn);
    z = z * sc + w;
    acc0 = acc0 * sc + w * xv.x;
    acc1 = acc1 * sc + w * xv.y;
    m = mn;
  }
  float inv = 1.f / (z + 1e-16f);
  float o0 = acc0 * inv + cbp[d0];
  float o1 = acc1 * inv + cbp[d0 + 1];
  if (relu_flag) { o0 = fmaxf(o0, 0.f); o1 = fmaxf(o1, 0.f); }
  *(float2*)&hout[(size_t)n * DD + d0] = make_float2(o0, o1);
}

// ---------------- head: out[g] = bout + sum_{n in g} h[n].Wout -------------------
__global__ void k_head_init(float* __restrict__ out, const float* __restrict__ bout, int G) {
  int i = blockIdx.x * blockDim.x + threadIdx.x;
  if (i < G) out[i] = bout[0];
}

__global__ __launch_bounds__(256) void k_head(const float* __restrict__ h,
    const int* __restrict__ bid, const float* __restrict__ Wout,
    float* __restrict__ out, int N) {
  int n = blockIdx.x * 4 + (threadIdx.x >> 6);
  if (n >= N) return;
  int lane = threadIdx.x & 63, d0 = lane * 2;
  float2 hv = *(const float2*)&h[(size_t)n * DD + d0];
  float v = hv.x * Wout[d0] + hv.y * Wout[d0 + 1];
  v += __shfl_xor(v, 1);
  v += __shfl_xor(v, 2);
  v += __shfl_xor(v, 4);
  v += __shfl_xor(v, 8);
  v += __shfl_xor(v, 16);
  v += __shfl_xor(v, 32);
  if (lane == 0) atomicAdd(&out[bid[n]], v);
}

extern "C" void kernel_launch(void* const* d_in, const int* in_sizes, int n_in,
                              void* d_out, int out_size, void* d_ws, size_t ws_size,
                              hipStream_t stream) {
  const float* atom_tables = (const float*)d_in[0];
  const float* bond_table  = (const float*)d_in[1];
  const float* Wl   = (const float*)d_in[2];
  const float* bl   = (const float*)d_in[3];
  const float* Wr   = (const float*)d_in[4];
  const float* br   = (const float*)d_in[5];
  const float* We   = (const float*)d_in[6];
  const float* att  = (const float*)d_in[7];
  const float* cb   = (const float*)d_in[8];
  const float* Wout = (const float*)d_in[9];
  const float* bout = (const float*)d_in[10];
  const int* x      = (const int*)d_in[11];
  const int* ei     = (const int*)d_in[12];
  const int* eattr  = (const int*)d_in[13];
  const int* bid    = (const int*)d_in[14];

  int N = in_sizes[11] / 9;
  int E = in_sizes[13];
  int G = out_size;          // NTASK == 1
  int L = in_sizes[3] / DD;  // 4 layers

  char* p = (char*)d_ws;
  auto alloc = [&](size_t bytes) {
    char* r = p;
    p += (bytes + 255) & ~(size_t)255;
    return r;
  };
  // hx: h input / xr / h output (aliased — see kernel notes). 102.4 MB
  float* hx     = (float*)alloc((size_t)N * DD * 4);
  float* xl     = (float*)alloc((size_t)N * DD * 4);   // 102.4 MB
  float* e_emb  = (float*)alloc((size_t)E * 4 * 4);    // 6.4 MB
  float* sums   = (float*)alloc((size_t)N * 4 * 4);    // loop_attr, 3.2 MB
  int*   rowptr = (int*)alloc((size_t)(N + 1) * 4);
  int*   eid    = (int*)alloc((size_t)(E + N) * 4);
  float* cnt    = (float*)alloc((size_t)N * 4);
  int*   deg    = (int*)alloc((size_t)N * 4);
  int*   cursor = (int*)alloc((size_t)N * 4);
  int nblk = (N + 2047) / 2048;
  int*   bsums  = (int*)alloc((size_t)nblk * 4);
  ushort* Bhi   = (ushort*)alloc((size_t)L * 2 * 16384 * 2);  // 256 KB
  ushort* Blo   = (ushort*)alloc((size_t)L * 2 * 16384 * 2);  // 256 KB
  float* out    = (float*)d_out;

  // Diagnostic guard: if workspace is too small, launch nothing -> clean
  // absmax failure instead of a GPU memory fault.
  if ((size_t)(p - (char*)d_ws) > ws_size) return;

  hipLaunchKernelGGL(k_atom_enc, dim3((N * DD + 255) / 256), dim3(256), 0, stream,
                     x, atom_tables, hx, N);
  hipLaunchKernelGGL(k_init, dim3((N + 255) / 256), dim3(256), 0, stream,
                     deg, cnt, sums, N);
  hipLaunchKernelGGL(k_edge_count, dim3((E + 255) / 256), dim3(256), 0, stream,
                     ei, eattr, bond_table, e_emb, sums, cnt, deg, E);
  hipLaunchKernelGGL(k_scan_block, dim3(nblk), dim3(256), 0, stream, deg, bsums, N);
  hipLaunchKernelGGL(k_scan_top, dim3(1), dim3(64), 0, stream, bsums, rowptr, nblk, N);
  hipLaunchKernelGGL(k_scan_down, dim3(nblk), dim3(256), 0, stream,
                     deg, bsums, rowptr, cursor, N);
  hipLaunchKernelGGL(k_scatter, dim3((E + N + 255) / 256), dim3(256), 0, stream,
                     ei, cursor, eid, E, N);
  hipLaunchKernelGGL(k_loopattr, dim3((N * 4 + 255) / 256), dim3(256), 0, stream,
                     sums, cnt, N);
  {
    int total = L * 2 * 4 * 8 * 64;
    hipLaunchKernelGGL(k_wpack, dim3((total + 255) / 256), dim3(256), 0, stream,
                       Wl, Wr, Bhi, Blo, L);
  }

  for (int l = 0; l < L; l++) {
    const ushort* bhiL = Bhi + (size_t)(l * 2 + 0) * 16384;
    const ushort* bhiR = Bhi + (size_t)(l * 2 + 1) * 16384;
    const ushort* bloL = Blo + (size_t)(l * 2 + 0) * 16384;
    const ushort* bloR = Blo + (size_t)(l * 2 + 1) * 16384;
    // writes xl, and xr -> hx (aliases input h; safe, see kernel note)
    hipLaunchKernelGGL(k_gemm2_mfma, dim3((N + 63) / 64), dim3(256), 0, stream,
                       hx, bhiL, bloL, bhiR, bloR,
                       bl + (size_t)l * DD, br + (size_t)l * DD, xl, hx, N);
    // reads xr from hx (own row), writes new h into hx (own row)
    hipLaunchKernelGGL(k_attn, dim3((N + 3) / 4), dim3(256), 0, stream,
                       xl, hx, e_emb, sums, ei, rowptr, eid,
                       We + (size_t)l * NHEAD * DD, att + (size_t)l * NHEAD * CHAN,
                       cb + (size_t)l * DD, hx, N, E, (l < L - 1) ? 1 : 0);
  }

  hipLaunchKernelGGL(k_head_init, dim3((G + 255) / 256), dim3(256), 0, stream,
                     out, bout, G);
  hipLaunchKernelGGL(k_head, dim3((N + 3) / 4), dim3(256), 0, stream,
                     hx, bid, Wout, out, N);
}

// Round 6
// 1264.673 us; speedup vs baseline: 1.5238x; 1.0249x over previous
//
#include <hip/hip_runtime.h>
#include <hip/hip_bf16.h>

#define DD 128
#define NHEAD 4
#define CHAN 32
#define NEG 0.2f

typedef short bf16x8 __attribute__((ext_vector_type(8)));
typedef float f32x4 __attribute__((ext_vector_type(4)));

__device__ inline ushort f2bf(float x) {
  unsigned u = __float_as_uint(x);
  return (ushort)((u + 0x7FFF + ((u >> 16) & 1)) >> 16);
}

// ---------------- atom encoder: h[n,d] = sum_f tab[f, x[n,f], d] ----------------
__global__ void k_atom_enc(const int* __restrict__ x, const float* __restrict__ tab,
                           float* __restrict__ h, int N) {
  int idx = blockIdx.x * blockDim.x + threadIdx.x;
  if (idx >= N * DD) return;
  int n = idx >> 7, d = idx & 127;
  const int* xr = x + n * 9;
  float s = 0.f;
#pragma unroll
  for (int f = 0; f < 9; f++) {
    int v = xr[f];
    s += tab[(f * 16 + v) * DD + d];
  }
  h[idx] = s;
}

// ---------------- init deg(=1 self loop), cnt, sums ----------------
__global__ void k_init(int* __restrict__ deg, float* __restrict__ cnt,
                       float* __restrict__ sums, int N) {
  int i = blockIdx.x * blockDim.x + threadIdx.x;
  if (i >= N) return;
  deg[i] = 1;
  cnt[i] = 0.f;
  sums[i * 4 + 0] = 0.f; sums[i * 4 + 1] = 0.f;
  sums[i * 4 + 2] = 0.f; sums[i * 4 + 3] = 0.f;
}

// ---------------- per real edge: bond emb, per-dst sums/cnt/deg ----------------
__global__ void k_edge_count(const int* __restrict__ ei, const int* __restrict__ eattr,
                             const float* __restrict__ btab, float* __restrict__ e_emb,
                             float* __restrict__ sums, float* __restrict__ cnt,
                             int* __restrict__ deg, int E) {
  int e = blockIdx.x * blockDim.x + threadIdx.x;
  if (e >= E) return;
  int d = ei[E + e];
  int a = eattr[e];
  float f0 = btab[a * 4 + 0], f1 = btab[a * 4 + 1];
  float f2 = btab[a * 4 + 2], f3 = btab[a * 4 + 3];
  e_emb[e * 4 + 0] = f0; e_emb[e * 4 + 1] = f1;
  e_emb[e * 4 + 2] = f2; e_emb[e * 4 + 3] = f3;
  atomicAdd(&sums[d * 4 + 0], f0);
  atomicAdd(&sums[d * 4 + 1], f1);
  atomicAdd(&sums[d * 4 + 2], f2);
  atomicAdd(&sums[d * 4 + 3], f3);
  atomicAdd(&cnt[d], 1.0f);
  atomicAdd(&deg[d], 1);
}

// ---------------- loop_attr (in-place on sums) ----------------
__global__ void k_loopattr(float* __restrict__ sums, const float* __restrict__ cnt, int N) {
  int i = blockIdx.x * blockDim.x + threadIdx.x;
  if (i >= N * 4) return;
  sums[i] = sums[i] / fmaxf(cnt[i >> 2], 1.0f);
}

// ---------------- scan: chunk = 2048 (256 thr x 8 items) ----------------
__global__ void k_scan_block(const int* __restrict__ deg, int* __restrict__ bsums, int N) {
  __shared__ int sh[256];
  int t = threadIdx.x;
  int base = blockIdx.x * 2048 + t * 8;
  int tot = 0;
#pragma unroll
  for (int i = 0; i < 8; i++) tot += (base + i < N) ? deg[base + i] : 0;
  sh[t] = tot;
  __syncthreads();
  for (int off = 128; off > 0; off >>= 1) {
    if (t < off) sh[t] += sh[t + off];
    __syncthreads();
  }
  if (t == 0) bsums[blockIdx.x] = sh[0];
}

__global__ void k_scan_top(int* __restrict__ bsums, int* __restrict__ rowptr,
                           int nblk, int N) {
  if (threadIdx.x == 0 && blockIdx.x == 0) {
    int run = 0;
    for (int b = 0; b < nblk; b++) { int v = bsums[b]; bsums[b] = run; run += v; }
    rowptr[N] = run;
  }
}

__global__ void k_scan_down(const int* __restrict__ deg, const int* __restrict__ bsums,
                            int* __restrict__ rowptr, int* __restrict__ cursor, int N) {
  __shared__ int sh[256];
  int t = threadIdx.x;
  int base = blockIdx.x * 2048 + t * 8;
  int v[8]; int tot = 0;
#pragma unroll
  for (int i = 0; i < 8; i++) { v[i] = (base + i < N) ? deg[base + i] : 0; tot += v[i]; }
  sh[t] = tot;
  __syncthreads();
  // Hillis-Steele inclusive scan
  for (int off = 1; off < 256; off <<= 1) {
    int xv = (t >= off) ? sh[t - off] : 0;
    __syncthreads();
    sh[t] += xv;
    __syncthreads();
  }
  int run = bsums[blockIdx.x] + sh[t] - tot;
#pragma unroll
  for (int i = 0; i < 8; i++) {
    if (base + i < N) { rowptr[base + i] = run; cursor[base + i] = run; run += v[i]; }
  }
}

// ---------------- scatter edge ids into CSR (order within segment irrelevant) -----
__global__ void k_scatter(const int* __restrict__ ei, int* __restrict__ cursor,
                          int* __restrict__ eid, int E, int N) {
  int t = blockIdx.x * blockDim.x + threadIdx.x;
  if (t >= E + N) return;
  int d = (t < E) ? ei[E + t] : (t - E);
  int pos = atomicAdd(&cursor[d], 1);
  eid[pos] = t;
}

// ---------------- W prepack: bf16 hi/lo split into MFMA fragment order -----------
// B frag for (layer,mat,kb,nt): lane l, elem j holds W[kb*32+(l>>4)*8+j][nt*16+(l&15)]
// stored contiguously so the GEMM reads one 16B load per frag.
__global__ void k_wpack(const float* __restrict__ Wl, const float* __restrict__ Wr,
                        ushort* __restrict__ Bhi, ushort* __restrict__ Blo, int L) {
  int tid = blockIdx.x * blockDim.x + threadIdx.x;
  int total = L * 2 * 4 * 8 * 64;
  if (tid >= total) return;
  int lane = tid & 63;
  int nt = (tid >> 6) & 7;
  int kb = (tid >> 9) & 3;
  int mat = (tid >> 11) & 1;
  int layer = tid >> 12;
  const float* W = (mat ? Wr : Wl) + (size_t)layer * DD * DD;
  int kbase = kb * 32 + (lane >> 4) * 8;
  int n = nt * 16 + (lane & 15);
  size_t out = (size_t)(layer * 2 + mat) * 16384 +
               ((size_t)(kb * 8 + nt) * 64 + lane) * 8;
#pragma unroll
  for (int j = 0; j < 8; j++) {
    float xv = W[(size_t)(kbase + j) * DD + n];
    ushort h_ = f2bf(xv);
    float fh = __uint_as_float((unsigned)h_ << 16);
    ushort l_ = f2bf(xv - fh);
    Bhi[out + j] = h_;
    Blo[out + j] = l_;
  }
}

// ---------------- fused xl/xr GEMM via bf16x3 MFMA ------------------------------
// 64 atoms x 128 outs x K=128, both mats. 4 waves; wave w: 4 M-tiles x N-tiles
// {2w,2w+1} x 2 mats. A staged in LDS as hi/lo bf16, XOR-swizzled (conflict-free
// ds_read_b128). B frags streamed from prepacked global (L2-hot, 16B/lane).
// NOTE: xr may ALIAS h (all h reads precede __syncthreads; stores data-depend).
__global__ __launch_bounds__(256) void k_gemm2_mfma(const float* h,
    const ushort* __restrict__ bhiL, const ushort* __restrict__ bloL,
    const ushort* __restrict__ bhiR, const ushort* __restrict__ bloR,
    const float* __restrict__ bl, const float* __restrict__ br,
    float* xl, float* xr, int N) {
  __shared__ ushort sAhi[64 * 128];
  __shared__ ushort sAlo[64 * 128];
  int t = threadIdx.x;
  int A0 = blockIdx.x * 64;
  // ---- stage h tile, split to bf16 hi/lo in LDS ----
  {
    int a = t >> 2;
    int kq = (t & 3) * 32;
    int n = A0 + a;
    const float* hp = &h[(size_t)n * DD + kq];
    int swz = (a & 7) << 4;
    int rowb = a * 256;
#pragma unroll
    for (int i = 0; i < 8; i++) {
      float4 v = (n < N) ? *(const float4*)(hp + i * 4) : make_float4(0, 0, 0, 0);
      float fv[4] = {v.x, v.y, v.z, v.w};
      ushort hiw[4], low[4];
#pragma unroll
      for (int j = 0; j < 4; j++) {
        ushort h_ = f2bf(fv[j]);
        float fh = __uint_as_float((unsigned)h_ << 16);
        hiw[j] = h_;
        low[j] = f2bf(fv[j] - fh);
      }
      int inrow = (kq + i * 4) * 2;           // byte offset within 256B row
      int off = rowb + (inrow ^ swz);
      *(ushort4*)((char*)sAhi + off) = make_ushort4(hiw[0], hiw[1], hiw[2], hiw[3]);
      *(ushort4*)((char*)sAlo + off) = make_ushort4(low[0], low[1], low[2], low[3]);
    }
  }
  __syncthreads();

  int lane = t & 63;
  int w = t >> 6;
  int arow = lane & 15;
  int acol = (lane >> 4) * 16;                // byte offset of k-group within row
  int swzr = (arow & 7) << 4;

  f32x4 accL[4][2], accR[4][2];
#pragma unroll
  for (int mt = 0; mt < 4; mt++)
#pragma unroll
    for (int nti = 0; nti < 2; nti++) {
      accL[mt][nti] = (f32x4){0.f, 0.f, 0.f, 0.f};
      accR[mt][nti] = (f32x4){0.f, 0.f, 0.f, 0.f};
    }

  for (int kb = 0; kb < 4; kb++) {
    bf16x8 ahi[4], alo[4];
#pragma unroll
    for (int mt = 0; mt < 4; mt++) {
      int abyte = (mt * 16 + arow) * 256 + ((kb * 64 + acol) ^ swzr);
      ahi[mt] = *(const bf16x8*)((const char*)sAhi + abyte);
      alo[mt] = *(const bf16x8*)((const char*)sAlo + abyte);
    }
#pragma unroll
    for (int nti = 0; nti < 2; nti++) {
      int nt = w * 2 + nti;
      size_t fo = ((size_t)(kb * 8 + nt) * 64 + lane) * 8;
      bf16x8 bhl = *(const bf16x8*)(bhiL + fo);
      bf16x8 bll = *(const bf16x8*)(bloL + fo);
      bf16x8 bhr = *(const bf16x8*)(bhiR + fo);
      bf16x8 blr = *(const bf16x8*)(bloR + fo);
#pragma unroll
      for (int mt = 0; mt < 4; mt++) {
        accL[mt][nti] = __builtin_amdgcn_mfma_f32_16x16x32_bf16(ahi[mt], bhl, accL[mt][nti], 0, 0, 0);
        accR[mt][nti] = __builtin_amdgcn_mfma_f32_16x16x32_bf16(ahi[mt], bhr, accR[mt][nti], 0, 0, 0);
        accL[mt][nti] = __builtin_amdgcn_mfma_f32_16x16x32_bf16(ahi[mt], bll, accL[mt][nti], 0, 0, 0);
        accR[mt][nti] = __builtin_amdgcn_mfma_f32_16x16x32_bf16(ahi[mt], blr, accR[mt][nti], 0, 0, 0);
        accL[mt][nti] = __builtin_amdgcn_mfma_f32_16x16x32_bf16(alo[mt], bhl, accL[mt][nti], 0, 0, 0);
        accR[mt][nti] = __builtin_amdgcn_mfma_f32_16x16x32_bf16(alo[mt], bhr, accR[mt][nti], 0, 0, 0);
      }
    }
  }

  // ---- epilogue: D row=(lane>>4)*4+r, col=lane&15 ----
  int col = lane & 15;
  int rgrp = (lane >> 4) * 4;
#pragma unroll
  for (int nti = 0; nti < 2; nti++) {
    int n = (w * 2 + nti) * 16 + col;
    float bLv = bl[n], bRv = br[n];
#pragma unroll
    for (int mt = 0; mt < 4; mt++) {
#pragma unroll
      for (int r = 0; r < 4; r++) {
        int atom = A0 + mt * 16 + rgrp + r;
        if (atom < N) {
          xl[(size_t)atom * DD + n] = accL[mt][nti][r] + bLv;
          xr[(size_t)atom * DD + n] = accR[mt][nti][r] + bRv;
        }
      }
    }
  }
}

// ---------------- node-parallel attention, online softmax, 4-edge batched gathers -
// Batch issues 4 independent eid->ei->xl load chains (clamped to r1-1, no
// divergent loads) before the sequential softmax updates => ~4x memory-level
// parallelism on the gather path (was 1 outstanding row/wave).
// Last layer (flags&2): fuse linear head (butterfly + 1 atomicAdd), skip h write.
// NOTE: xr and hout may ALIAS (wave reads only its own row at start, writes its
// own row at end; no cross-row reads of that buffer). No __restrict__ on them.
__global__ __launch_bounds__(256) void k_attn(
    const float* __restrict__ xl, const float* xr,
    const float* __restrict__ e_emb, const float* __restrict__ la,
    const int* __restrict__ ei, const int* __restrict__ rowptr,
    const int* __restrict__ eid,
    const float* __restrict__ Wep, const float* __restrict__ attp,
    const float* __restrict__ cbp,
    const float* __restrict__ Woutp, const int* __restrict__ bid,
    float* __restrict__ outp,
    float* hout, int N, int E, int flags) {
  int wid = threadIdx.x >> 6;
  int lane = threadIdx.x & 63;
  int n = blockIdx.x * 4 + wid;
  if (n >= N) return;
  int d0 = lane * 2;
  float we0[4], we1[4];
#pragma unroll
  for (int j = 0; j < 4; j++) {
    we0[j] = Wep[j * DD + d0];
    we1[j] = Wep[j * DD + d0 + 1];
  }
  int hh = lane >> 4;
  float a0 = attp[hh * 32 + (d0 & 31)];
  float a1 = attp[hh * 32 + ((d0 + 1) & 31)];
  float2 xr2 = *(const float2*)&xr[(size_t)n * DD + d0];
  float m = -3.0e38f, z = 0.f, acc0 = 0.f, acc1 = 0.f;
  int r0 = rowptr[n], r1 = rowptr[n + 1];
  for (int p0 = r0; p0 < r1; p0 += 4) {
    int nb = r1 - p0; nb = nb > 4 ? 4 : nb;
    int ss[4]; float4 ff[4]; float2 xv[4];
#pragma unroll
    for (int j = 0; j < 4; j++) {
      int p = p0 + j; p = (p < r1) ? p : (r1 - 1);   // clamp: dup last edge, masked below
      int e = eid[p];
      bool re = e < E;
      ss[j] = re ? ei[e] : n;
      ff[j] = re ? *(const float4*)&e_emb[(size_t)e * 4]
                 : *(const float4*)&la[(size_t)n * 4];
    }
#pragma unroll
    for (int j = 0; j < 4; j++)
      xv[j] = *(const float2*)&xl[(size_t)ss[j] * DD + d0];
#pragma unroll
    for (int j = 0; j < 4; j++) {
      if (j < nb) {
        float ee0 = ff[j].x * we0[0] + ff[j].y * we0[1] + ff[j].z * we0[2] + ff[j].w * we0[3];
        float ee1 = ff[j].x * we1[0] + ff[j].y * we1[1] + ff[j].z * we1[2] + ff[j].w * we1[3];
        float g0 = xv[j].x + xr2.x + ee0; g0 = g0 > 0.f ? g0 : NEG * g0;
        float g1 = xv[j].y + xr2.y + ee1; g1 = g1 > 0.f ? g1 : NEG * g1;
        float pv = g0 * a0 + g1 * a1;
        pv += __shfl_xor(pv, 1);
        pv += __shfl_xor(pv, 2);
        pv += __shfl_xor(pv, 4);
        pv += __shfl_xor(pv, 8);
        float mn = fmaxf(m, pv);
        float sc = __expf(m - mn);
        float w  = __expf(pv - mn);
        z = z * sc + w;
        acc0 = acc0 * sc + w * xv[j].x;
        acc1 = acc1 * sc + w * xv[j].y;
        m = mn;
      }
    }
  }
  float inv = 1.f / (z + 1e-16f);
  float o0 = acc0 * inv + cbp[d0];
  float o1 = acc1 * inv + cbp[d0 + 1];
  if (flags & 1) { o0 = fmaxf(o0, 0.f); o1 = fmaxf(o1, 0.f); }
  if (flags & 2) {
    // fused head: out[bid[n]] += sum_d h[n,d]*Wout[d]
    float v = o0 * Woutp[d0] + o1 * Woutp[d0 + 1];
    v += __shfl_xor(v, 1);
    v += __shfl_xor(v, 2);
    v += __shfl_xor(v, 4);
    v += __shfl_xor(v, 8);
    v += __shfl_xor(v, 16);
    v += __shfl_xor(v, 32);
    if (lane == 0) atomicAdd(&outp[bid[n]], v);
  } else {
    *(float2*)&hout[(size_t)n * DD + d0] = make_float2(o0, o1);
  }
}

// ---------------- out init: out[g] = bout ----------------------------------------
__global__ void k_head_init(float* __restrict__ out, const float* __restrict__ bout, int G) {
  int i = blockIdx.x * blockDim.x + threadIdx.x;
  if (i < G) out[i] = bout[0];
}

extern "C" void kernel_launch(void* const* d_in, const int* in_sizes, int n_in,
                              void* d_out, int out_size, void* d_ws, size_t ws_size,
                              hipStream_t stream) {
  const float* atom_tables = (const float*)d_in[0];
  const float* bond_table  = (const float*)d_in[1];
  const float* Wl   = (const float*)d_in[2];
  const float* bl   = (const float*)d_in[3];
  const float* Wr   = (const float*)d_in[4];
  const float* br   = (const float*)d_in[5];
  const float* We   = (const float*)d_in[6];
  const float* att  = (const float*)d_in[7];
  const float* cb   = (const float*)d_in[8];
  const float* Wout = (const float*)d_in[9];
  const float* bout = (const float*)d_in[10];
  const int* x      = (const int*)d_in[11];
  const int* ei     = (const int*)d_in[12];
  const int* eattr  = (const int*)d_in[13];
  const int* bid    = (const int*)d_in[14];

  int N = in_sizes[11] / 9;
  int E = in_sizes[13];
  int G = out_size;          // NTASK == 1
  int L = in_sizes[3] / DD;  // 4 layers

  char* p = (char*)d_ws;
  auto alloc = [&](size_t bytes) {
    char* r = p;
    p += (bytes + 255) & ~(size_t)255;
    return r;
  };
  // hx: h input / xr / h output (aliased — see kernel notes). 102.4 MB
  float* hx     = (float*)alloc((size_t)N * DD * 4);
  float* xl     = (float*)alloc((size_t)N * DD * 4);   // 102.4 MB
  float* e_emb  = (float*)alloc((size_t)E * 4 * 4);    // 6.4 MB
  float* sums   = (float*)alloc((size_t)N * 4 * 4);    // loop_attr, 3.2 MB
  int*   rowptr = (int*)alloc((size_t)(N + 1) * 4);
  int*   eid    = (int*)alloc((size_t)(E + N) * 4);
  float* cnt    = (float*)alloc((size_t)N * 4);
  int*   deg    = (int*)alloc((size_t)N * 4);
  int*   cursor = (int*)alloc((size_t)N * 4);
  int nblk = (N + 2047) / 2048;
  int*   bsums  = (int*)alloc((size_t)nblk * 4);
  ushort* Bhi   = (ushort*)alloc((size_t)L * 2 * 16384 * 2);  // 256 KB
  ushort* Blo   = (ushort*)alloc((size_t)L * 2 * 16384 * 2);  // 256 KB
  float* out    = (float*)d_out;

  // Diagnostic guard: if workspace is too small, launch nothing -> clean
  // absmax failure instead of a GPU memory fault.
  if ((size_t)(p - (char*)d_ws) > ws_size) return;

  hipLaunchKernelGGL(k_atom_enc, dim3((N * DD + 255) / 256), dim3(256), 0, stream,
                     x, atom_tables, hx, N);
  hipLaunchKernelGGL(k_init, dim3((N + 255) / 256), dim3(256), 0, stream,
                     deg, cnt, sums, N);
  hipLaunchKernelGGL(k_edge_count, dim3((E + 255) / 256), dim3(256), 0, stream,
                     ei, eattr, bond_table, e_emb, sums, cnt, deg, E);
  hipLaunchKernelGGL(k_scan_block, dim3(nblk), dim3(256), 0, stream, deg, bsums, N);
  hipLaunchKernelGGL(k_scan_top, dim3(1), dim3(64), 0, stream, bsums, rowptr, nblk, N);
  hipLaunchKernelGGL(k_scan_down, dim3(nblk), dim3(256), 0, stream,
                     deg, bsums, rowptr, cursor, N);
  hipLaunchKernelGGL(k_scatter, dim3((E + N + 255) / 256), dim3(256), 0, stream,
                     ei, cursor, eid, E, N);
  hipLaunchKernelGGL(k_loopattr, dim3((N * 4 + 255) / 256), dim3(256), 0, stream,
                     sums, cnt, N);
  {
    int total = L * 2 * 4 * 8 * 64;
    hipLaunchKernelGGL(k_wpack, dim3((total + 255) / 256), dim3(256), 0, stream,
                       Wl, Wr, Bhi, Blo, L);
  }
  // out init early; last attn layer atomically accumulates into it
  hipLaunchKernelGGL(k_head_init, dim3((G + 255) / 256), dim3(256), 0, stream,
                     out, bout, G);

  for (int l = 0; l < L; l++) {
    const ushort* bhiL = Bhi + (size_t)(l * 2 + 0) * 16384;
    const ushort* bhiR = Bhi + (size_t)(l * 2 + 1) * 16384;
    const ushort* bloL = Blo + (size_t)(l * 2 + 0) * 16384;
    const ushort* bloR = Blo + (size_t)(l * 2 + 1) * 16384;
    // writes xl, and xr -> hx (aliases input h; safe, see kernel note)
    hipLaunchKernelGGL(k_gemm2_mfma, dim3((N + 63) / 64), dim3(256), 0, stream,
                       hx, bhiL, bloL, bhiR, bloR,
                       bl + (size_t)l * DD, br + (size_t)l * DD, xl, hx, N);
    int flags = (l < L - 1) ? 1 : 2;   // relu for inner layers; head-fusion on last
    hipLaunchKernelGGL(k_attn, dim3((N + 3) / 4), dim3(256), 0, stream,
                       xl, hx, e_emb, sums, ei, rowptr, eid,
                       We + (size_t)l * NHEAD * DD, att + (size_t)l * NHEAD * CHAN,
                       cb + (size_t)l * DD, Wout, bid, out, hx, N, E, flags);
  }
}

// Round 10
// 1231.168 us; speedup vs baseline: 1.5652x; 1.0272x over previous
//
#include <hip/hip_runtime.h>
#include <hip/hip_bf16.h>

#define DD 128
#define NHEAD 4
#define CHAN 32
#define NEG 0.2f

typedef short bf16x8 __attribute__((ext_vector_type(8)));
typedef float f32x4 __attribute__((ext_vector_type(4)));

__device__ inline ushort f2bf(float x) {
  unsigned u = __float_as_uint(x);
  return (ushort)((u + 0x7FFF + ((u >> 16) & 1)) >> 16);
}
__device__ inline float bf2f(ushort u) {
  return __uint_as_float((unsigned)u << 16);
}

// ---------------- atom encoder: h[n,d] = sum_f tab[f, x[n,f], d] ----------------
__global__ void k_atom_enc(const int* __restrict__ x, const float* __restrict__ tab,
                           float* __restrict__ h, int N) {
  int idx = blockIdx.x * blockDim.x + threadIdx.x;
  if (idx >= N * DD) return;
  int n = idx >> 7, d = idx & 127;
  const int* xr = x + n * 9;
  float s = 0.f;
#pragma unroll
  for (int f = 0; f < 9; f++) {
    int v = xr[f];
    s += tab[(f * 16 + v) * DD + d];
  }
  h[idx] = s;
}

// ---------------- init deg(=1 self loop), cnt, sums ----------------
__global__ void k_init(int* __restrict__ deg, float* __restrict__ cnt,
                       float* __restrict__ sums, int N) {
  int i = blockIdx.x * blockDim.x + threadIdx.x;
  if (i >= N) return;
  deg[i] = 1;
  cnt[i] = 0.f;
  sums[i * 4 + 0] = 0.f; sums[i * 4 + 1] = 0.f;
  sums[i * 4 + 2] = 0.f; sums[i * 4 + 3] = 0.f;
}

// ---------------- per real edge: bond emb, per-dst sums/cnt/deg ----------------
__global__ void k_edge_count(const int* __restrict__ ei, const int* __restrict__ eattr,
                             const float* __restrict__ btab, float* __restrict__ e_emb,
                             float* __restrict__ sums, float* __restrict__ cnt,
                             int* __restrict__ deg, int E) {
  int e = blockIdx.x * blockDim.x + threadIdx.x;
  if (e >= E) return;
  int d = ei[E + e];
  int a = eattr[e];
  float f0 = btab[a * 4 + 0], f1 = btab[a * 4 + 1];
  float f2 = btab[a * 4 + 2], f3 = btab[a * 4 + 3];
  e_emb[e * 4 + 0] = f0; e_emb[e * 4 + 1] = f1;
  e_emb[e * 4 + 2] = f2; e_emb[e * 4 + 3] = f3;
  atomicAdd(&sums[d * 4 + 0], f0);
  atomicAdd(&sums[d * 4 + 1], f1);
  atomicAdd(&sums[d * 4 + 2], f2);
  atomicAdd(&sums[d * 4 + 3], f3);
  atomicAdd(&cnt[d], 1.0f);
  atomicAdd(&deg[d], 1);
}

// ---------------- loop_attr (in-place on sums) ----------------
__global__ void k_loopattr(float* __restrict__ sums, const float* __restrict__ cnt, int N) {
  int i = blockIdx.x * blockDim.x + threadIdx.x;
  if (i >= N * 4) return;
  sums[i] = sums[i] / fmaxf(cnt[i >> 2], 1.0f);
}

// ---------------- scan: chunk = 2048 (256 thr x 8 items) ----------------
__global__ void k_scan_block(const int* __restrict__ deg, int* __restrict__ bsums, int N) {
  __shared__ int sh[256];
  int t = threadIdx.x;
  int base = blockIdx.x * 2048 + t * 8;
  int tot = 0;
#pragma unroll
  for (int i = 0; i < 8; i++) tot += (base + i < N) ? deg[base + i] : 0;
  sh[t] = tot;
  __syncthreads();
  for (int off = 128; off > 0; off >>= 1) {
    if (t < off) sh[t] += sh[t + off];
    __syncthreads();
  }
  if (t == 0) bsums[blockIdx.x] = sh[0];
}

__global__ void k_scan_top(int* __restrict__ bsums, int* __restrict__ rowptr,
                           int nblk, int N) {
  if (threadIdx.x == 0 && blockIdx.x == 0) {
    int run = 0;
    for (int b = 0; b < nblk; b++) { int v = bsums[b]; bsums[b] = run; run += v; }
    rowptr[N] = run;
  }
}

__global__ void k_scan_down(const int* __restrict__ deg, const int* __restrict__ bsums,
                            int* __restrict__ rowptr, int* __restrict__ cursor, int N) {
  __shared__ int sh[256];
  int t = threadIdx.x;
  int base = blockIdx.x * 2048 + t * 8;
  int v[8]; int tot = 0;
#pragma unroll
  for (int i = 0; i < 8; i++) { v[i] = (base + i < N) ? deg[base + i] : 0; tot += v[i]; }
  sh[t] = tot;
  __syncthreads();
  // Hillis-Steele inclusive scan
  for (int off = 1; off < 256; off <<= 1) {
    int xv = (t >= off) ? sh[t - off] : 0;
    __syncthreads();
    sh[t] += xv;
    __syncthreads();
  }
  int run = bsums[blockIdx.x] + sh[t] - tot;
#pragma unroll
  for (int i = 0; i < 8; i++) {
    if (base + i < N) { rowptr[base + i] = run; cursor[base + i] = run; run += v[i]; }
  }
}

// ---------------- scatter edge ids into CSR (order within segment irrelevant) -----
__global__ void k_scatter(const int* __restrict__ ei, int* __restrict__ cursor,
                          int* __restrict__ eid, int E, int N) {
  int t = blockIdx.x * blockDim.x + threadIdx.x;
  if (t >= E + N) return;
  int d = (t < E) ? ei[E + t] : (t - E);
  int pos = atomicAdd(&cursor[d], 1);
  eid[pos] = t;
}

// ---------------- W prepack: bf16 hi/lo split into MFMA fragment order -----------
__global__ void k_wpack(const float* __restrict__ Wl, const float* __restrict__ Wr,
                        ushort* __restrict__ Bhi, ushort* __restrict__ Blo, int L) {
  int tid = blockIdx.x * blockDim.x + threadIdx.x;
  int total = L * 2 * 4 * 8 * 64;
  if (tid >= total) return;
  int lane = tid & 63;
  int nt = (tid >> 6) & 7;
  int kb = (tid >> 9) & 3;
  int mat = (tid >> 11) & 1;
  int layer = tid >> 12;
  const float* W = (mat ? Wr : Wl) + (size_t)layer * DD * DD;
  int kbase = kb * 32 + (lane >> 4) * 8;
  int n = nt * 16 + (lane & 15);
  size_t out = (size_t)(layer * 2 + mat) * 16384 +
               ((size_t)(kb * 8 + nt) * 64 + lane) * 8;
#pragma unroll
  for (int j = 0; j < 8; j++) {
    float xv = W[(size_t)(kbase + j) * DD + n];
    ushort h_ = f2bf(xv);
    float fh = __uint_as_float((unsigned)h_ << 16);
    ushort l_ = f2bf(xv - fh);
    Bhi[out + j] = h_;
    Blo[out + j] = l_;
  }
}

// ---------------- fused xl/xr GEMM via bf16x3 MFMA ------------------------------
// Outputs are bf16 now: xl -> xlb (ushort, packed rows of 128), xr -> packed into
// the FIRST HALF of each hx f32 row (ushort stride 256/row). Aliasing safe: all h
// reads for this block's rows precede __syncthreads(); stores data-depend via LDS;
// blocks own disjoint rows.
__global__ __launch_bounds__(256) void k_gemm2_mfma(const float* h,
    const ushort* __restrict__ bhiL, const ushort* __restrict__ bloL,
    const ushort* __restrict__ bhiR, const ushort* __restrict__ bloR,
    const float* __restrict__ bl, const float* __restrict__ br,
    ushort* __restrict__ xlb, float* xr_rows, int N) {
  __shared__ ushort sAhi[64 * 128];
  __shared__ ushort sAlo[64 * 128];
  int t = threadIdx.x;
  int A0 = blockIdx.x * 64;
  // ---- stage h tile, split to bf16 hi/lo in LDS ----
  {
    int a = t >> 2;
    int kq = (t & 3) * 32;
    int n = A0 + a;
    const float* hp = &h[(size_t)n * DD + kq];
    int swz = (a & 7) << 4;
    int rowb = a * 256;
#pragma unroll
    for (int i = 0; i < 8; i++) {
      float4 v = (n < N) ? *(const float4*)(hp + i * 4) : make_float4(0, 0, 0, 0);
      float fv[4] = {v.x, v.y, v.z, v.w};
      ushort hiw[4], low[4];
#pragma unroll
      for (int j = 0; j < 4; j++) {
        ushort h_ = f2bf(fv[j]);
        float fh = __uint_as_float((unsigned)h_ << 16);
        hiw[j] = h_;
        low[j] = f2bf(fv[j] - fh);
      }
      int inrow = (kq + i * 4) * 2;           // byte offset within 256B row
      int off = rowb + (inrow ^ swz);
      *(ushort4*)((char*)sAhi + off) = make_ushort4(hiw[0], hiw[1], hiw[2], hiw[3]);
      *(ushort4*)((char*)sAlo + off) = make_ushort4(low[0], low[1], low[2], low[3]);
    }
  }
  __syncthreads();

  int lane = t & 63;
  int w = t >> 6;
  int arow = lane & 15;
  int acol = (lane >> 4) * 16;                // byte offset of k-group within row
  int swzr = (arow & 7) << 4;

  f32x4 accL[4][2], accR[4][2];
#pragma unroll
  for (int mt = 0; mt < 4; mt++)
#pragma unroll
    for (int nti = 0; nti < 2; nti++) {
      accL[mt][nti] = (f32x4){0.f, 0.f, 0.f, 0.f};
      accR[mt][nti] = (f32x4){0.f, 0.f, 0.f, 0.f};
    }

  for (int kb = 0; kb < 4; kb++) {
    bf16x8 ahi[4], alo[4];
#pragma unroll
    for (int mt = 0; mt < 4; mt++) {
      int abyte = (mt * 16 + arow) * 256 + ((kb * 64 + acol) ^ swzr);
      ahi[mt] = *(const bf16x8*)((const char*)sAhi + abyte);
      alo[mt] = *(const bf16x8*)((const char*)sAlo + abyte);
    }
#pragma unroll
    for (int nti = 0; nti < 2; nti++) {
      int nt = w * 2 + nti;
      size_t fo = ((size_t)(kb * 8 + nt) * 64 + lane) * 8;
      bf16x8 bhl = *(const bf16x8*)(bhiL + fo);
      bf16x8 bll = *(const bf16x8*)(bloL + fo);
      bf16x8 bhr = *(const bf16x8*)(bhiR + fo);
      bf16x8 blr = *(const bf16x8*)(bloR + fo);
#pragma unroll
      for (int mt = 0; mt < 4; mt++) {
        accL[mt][nti] = __builtin_amdgcn_mfma_f32_16x16x32_bf16(ahi[mt], bhl, accL[mt][nti], 0, 0, 0);
        accR[mt][nti] = __builtin_amdgcn_mfma_f32_16x16x32_bf16(ahi[mt], bhr, accR[mt][nti], 0, 0, 0);
        accL[mt][nti] = __builtin_amdgcn_mfma_f32_16x16x32_bf16(ahi[mt], bll, accL[mt][nti], 0, 0, 0);
        accR[mt][nti] = __builtin_amdgcn_mfma_f32_16x16x32_bf16(ahi[mt], blr, accR[mt][nti], 0, 0, 0);
        accL[mt][nti] = __builtin_amdgcn_mfma_f32_16x16x32_bf16(alo[mt], bhl, accL[mt][nti], 0, 0, 0);
        accR[mt][nti] = __builtin_amdgcn_mfma_f32_16x16x32_bf16(alo[mt], bhr, accR[mt][nti], 0, 0, 0);
      }
    }
  }

  // ---- epilogue: D row=(lane>>4)*4+r, col=lane&15; bf16 stores ----
  ushort* xru = (ushort*)xr_rows;             // first 256B of each 512B hx row
  int col = lane & 15;
  int rgrp = (lane >> 4) * 4;
#pragma unroll
  for (int nti = 0; nti < 2; nti++) {
    int n = (w * 2 + nti) * 16 + col;
    float bLv = bl[n], bRv = br[n];
#pragma unroll
    for (int mt = 0; mt < 4; mt++) {
#pragma unroll
      for (int r = 0; r < 4; r++) {
        int atom = A0 + mt * 16 + rgrp + r;
        if (atom < N) {
          xlb[(size_t)atom * DD + n]  = f2bf(accL[mt][nti][r] + bLv);
          xru[(size_t)atom * 256 + n] = f2bf(accR[mt][nti][r] + bRv);
        }
      }
    }
  }
}

// ---------------- node-parallel attention, online softmax, bf16 gathers ----------
// xl gathers are bf16 rows (256B) => half the L2-miss bytes. 4-edge batches with
// independent butterflies (ILP); padded slots handled by multiply-mask, not exec
// branches. Last layer (flags&2): fused head with per-block LDS pre-reduction
// (~4x fewer device atomics). xr read from first half of own hx row (bf16);
// hout (inner layers) writes full f32 row of hx afterwards - aliasing safe.
__global__ __launch_bounds__(256) void k_attn(
    const ushort* __restrict__ xlb, const float* xr_rows,
    const float* __restrict__ e_emb, const float* __restrict__ la,
    const int* __restrict__ ei, const int* __restrict__ rowptr,
    const int* __restrict__ eid,
    const float* __restrict__ Wep, const float* __restrict__ attp,
    const float* __restrict__ cbp,
    const float* __restrict__ Woutp, const int* __restrict__ bid,
    float* __restrict__ outp,
    float* hout, int N, int E, int flags) {
  __shared__ float sv[4];
  __shared__ int   sb[4];
  int wid = threadIdx.x >> 6;
  int lane = threadIdx.x & 63;
  int n = blockIdx.x * 4 + wid;
  bool act = n < N;
  int d0 = lane * 2;
  float o0 = 0.f, o1 = 0.f;
  if (act) {
    float we0[4], we1[4];
#pragma unroll
    for (int j = 0; j < 4; j++) {
      we0[j] = Wep[j * DD + d0];
      we1[j] = Wep[j * DD + d0 + 1];
    }
    int hh = lane >> 4;
    float a0 = attp[hh * 32 + (d0 & 31)];
    float a1 = attp[hh * 32 + ((d0 + 1) & 31)];
    const ushort* xru = (const ushort*)xr_rows;
    ushort2 xru2 = *(const ushort2*)&xru[(size_t)n * 256 + d0];
    float xr0 = bf2f(xru2.x), xr1 = bf2f(xru2.y);
    float4 la4 = *(const float4*)&la[(size_t)n * 4];
    float m = -3.0e38f, z = 0.f, acc0 = 0.f, acc1 = 0.f;
    int r0 = rowptr[n], r1 = rowptr[n + 1];
    for (int p0 = r0; p0 < r1; p0 += 4) {
      int ss[4]; float4 ff[4];
      float xv0[4], xv1[4], pv[4];
#pragma unroll
      for (int j = 0; j < 4; j++) {
        int p = p0 + j; p = (p < r1) ? p : (r1 - 1);   // clamp: dup last edge
        int e = eid[p];
        bool re = e < E;
        ss[j] = re ? ei[e] : n;
        ff[j] = re ? *(const float4*)&e_emb[(size_t)e * 4] : la4;
      }
#pragma unroll
      for (int j = 0; j < 4; j++) {
        ushort2 u = *(const ushort2*)&xlb[(size_t)ss[j] * DD + d0];
        xv0[j] = bf2f(u.x); xv1[j] = bf2f(u.y);
      }
#pragma unroll
      for (int j = 0; j < 4; j++) {
        float ee0 = ff[j].x * we0[0] + ff[j].y * we0[1] + ff[j].z * we0[2] + ff[j].w * we0[3];
        float ee1 = ff[j].x * we1[0] + ff[j].y * we1[1] + ff[j].z * we1[2] + ff[j].w * we1[3];
        float g0 = xv0[j] + xr0 + ee0; g0 = g0 > 0.f ? g0 : NEG * g0;
        float g1 = xv1[j] + xr1 + ee1; g1 = g1 > 0.f ? g1 : NEG * g1;
        pv[j] = g0 * a0 + g1 * a1;
      }
      // 4 independent butterflies (ILP across j)
#pragma unroll
      for (int j = 0; j < 4; j++) {
        pv[j] += __shfl_xor(pv[j], 1);
        pv[j] += __shfl_xor(pv[j], 2);
        pv[j] += __shfl_xor(pv[j], 4);
        pv[j] += __shfl_xor(pv[j], 8);
      }
#pragma unroll
      for (int j = 0; j < 4; j++) {
        float msk = (p0 + j < r1) ? 1.f : 0.f;   // padded pv duplicates a real edge
        float mn = fmaxf(m, pv[j]);              // -> max unchanged by padding
        float sc = __expf(m - mn);
        float wj = __expf(pv[j] - mn) * msk;
        z = z * sc + wj;
        acc0 = acc0 * sc + wj * xv0[j];
        acc1 = acc1 * sc + wj * xv1[j];
        m = mn;
      }
    }
    float inv = 1.f / (z + 1e-16f);
    o0 = acc0 * inv + cbp[d0];
    o1 = acc1 * inv + cbp[d0 + 1];
    if (flags & 1) { o0 = fmaxf(o0, 0.f); o1 = fmaxf(o1, 0.f); }
    if (!(flags & 2)) {
      *(float2*)&hout[(size_t)n * DD + d0] = make_float2(o0, o1);
    }
  }
  if (flags & 2) {
    // fused head with per-block LDS pre-reduction
    float v = o0 * Woutp[d0] + o1 * Woutp[d0 + 1];
    v += __shfl_xor(v, 1);
    v += __shfl_xor(v, 2);
    v += __shfl_xor(v, 4);
    v += __shfl_xor(v, 8);
    v += __shfl_xor(v, 16);
    v += __shfl_xor(v, 32);
    if (lane == 0) {
      sv[wid] = v;
      sb[wid] = act ? bid[n] : -1;
    }
    __syncthreads();
    if (threadIdx.x == 0) {
      int i = 0;
      while (i < 4) {
        int b = sb[i];
        if (b < 0) { i++; continue; }
        float s = sv[i];
        int j = i + 1;
        while (j < 4 && sb[j] == b) { s += sv[j]; j++; }
        atomicAdd(&outp[b], s);
        i = j;
      }
    }
  }
}

// ---------------- out init: out[g] = bout ----------------------------------------
__global__ void k_head_init(float* __restrict__ out, const float* __restrict__ bout, int G) {
  int i = blockIdx.x * blockDim.x + threadIdx.x;
  if (i < G) out[i] = bout[0];
}

extern "C" void kernel_launch(void* const* d_in, const int* in_sizes, int n_in,
                              void* d_out, int out_size, void* d_ws, size_t ws_size,
                              hipStream_t stream) {
  const float* atom_tables = (const float*)d_in[0];
  const float* bond_table  = (const float*)d_in[1];
  const float* Wl   = (const float*)d_in[2];
  const float* bl   = (const float*)d_in[3];
  const float* Wr   = (const float*)d_in[4];
  const float* br   = (const float*)d_in[5];
  const float* We   = (const float*)d_in[6];
  const float* att  = (const float*)d_in[7];
  const float* cb   = (const float*)d_in[8];
  const float* Wout = (const float*)d_in[9];
  const float* bout = (const float*)d_in[10];
  const int* x      = (const int*)d_in[11];
  const int* ei     = (const int*)d_in[12];
  const int* eattr  = (const int*)d_in[13];
  const int* bid    = (const int*)d_in[14];

  int N = in_sizes[11] / 9;
  int E = in_sizes[13];
  int G = out_size;          // NTASK == 1
  int L = in_sizes[3] / DD;  // 4 layers

  char* p = (char*)d_ws;
  auto alloc = [&](size_t bytes) {
    char* r = p;
    p += (bytes + 255) & ~(size_t)255;
    return r;
  };
  // hx: h input / xr(bf16, first half of each row) / h output. 102.4 MB
  float*  hx     = (float*)alloc((size_t)N * DD * 4);
  ushort* xlb    = (ushort*)alloc((size_t)N * DD * 2);  // 51.2 MB bf16
  float*  e_emb  = (float*)alloc((size_t)E * 4 * 4);    // 6.4 MB
  float*  sums   = (float*)alloc((size_t)N * 4 * 4);    // loop_attr, 3.2 MB
  int*    rowptr = (int*)alloc((size_t)(N + 1) * 4);
  int*    eid    = (int*)alloc((size_t)(E + N) * 4);
  float*  cnt    = (float*)alloc((size_t)N * 4);
  int*    deg    = (int*)alloc((size_t)N * 4);
  int*    cursor = (int*)alloc((size_t)N * 4);
  int nblk = (N + 2047) / 2048;
  int*    bsums  = (int*)alloc((size_t)nblk * 4);
  ushort* Bhi    = (ushort*)alloc((size_t)L * 2 * 16384 * 2);  // 256 KB
  ushort* Blo    = (ushort*)alloc((size_t)L * 2 * 16384 * 2);  // 256 KB
  float*  out    = (float*)d_out;

  // Diagnostic guard: if workspace is too small, launch nothing -> clean
  // absmax failure instead of a GPU memory fault.
  if ((size_t)(p - (char*)d_ws) > ws_size) return;

  hipLaunchKernelGGL(k_atom_enc, dim3((N * DD + 255) / 256), dim3(256), 0, stream,
                     x, atom_tables, hx, N);
  hipLaunchKernelGGL(k_init, dim3((N + 255) / 256), dim3(256), 0, stream,
                     deg, cnt, sums, N);
  hipLaunchKernelGGL(k_edge_count, dim3((E + 255) / 256), dim3(256), 0, stream,
                     ei, eattr, bond_table, e_emb, sums, cnt, deg, E);
  hipLaunchKernelGGL(k_scan_block, dim3(nblk), dim3(256), 0, stream, deg, bsums, N);
  hipLaunchKernelGGL(k_scan_top, dim3(1), dim3(64), 0, stream, bsums, rowptr, nblk, N);
  hipLaunchKernelGGL(k_scan_down, dim3(nblk), dim3(256), 0, stream,
                     deg, bsums, rowptr, cursor, N);
  hipLaunchKernelGGL(k_scatter, dim3((E + N + 255) / 256), dim3(256), 0, stream,
                     ei, cursor, eid, E, N);
  hipLaunchKernelGGL(k_loopattr, dim3((N * 4 + 255) / 256), dim3(256), 0, stream,
                     sums, cnt, N);
  {
    int total = L * 2 * 4 * 8 * 64;
    hipLaunchKernelGGL(k_wpack, dim3((total + 255) / 256), dim3(256), 0, stream,
                       Wl, Wr, Bhi, Blo, L);
  }
  // out init early; last attn layer atomically accumulates into it
  hipLaunchKernelGGL(k_head_init, dim3((G + 255) / 256), dim3(256), 0, stream,
                     out, bout, G);

  for (int l = 0; l < L; l++) {
    const ushort* bhiL = Bhi + (size_t)(l * 2 + 0) * 16384;
    const ushort* bhiR = Bhi + (size_t)(l * 2 + 1) * 16384;
    const ushort* bloL = Blo + (size_t)(l * 2 + 0) * 16384;
    const ushort* bloR = Blo + (size_t)(l * 2 + 1) * 16384;
    // writes xlb (bf16), and xr(bf16) -> first half of hx rows (aliasing safe)
    hipLaunchKernelGGL(k_gemm2_mfma, dim3((N + 63) / 64), dim3(256), 0, stream,
                       hx, bhiL, bloL, bhiR, bloR,
                       bl + (size_t)l * DD, br + (size_t)l * DD, xlb, hx, N);
    int flags = (l < L - 1) ? 1 : 2;   // relu inner; head-fusion last
    hipLaunchKernelGGL(k_attn, dim3((N + 3) / 4), dim3(256), 0, stream,
                       xlb, hx, e_emb, sums, ei, rowptr, eid,
                       We + (size_t)l * NHEAD * DD, att + (size_t)l * NHEAD * CHAN,
                       cb + (size_t)l * DD, Wout, bid, out, hx, N, E, flags);
  }
}